// Round 3
// baseline (173.906 us; speedup 1.0000x reference)
//
#include <hip/hip_runtime.h>
#include <math.h>

#define NCAT  5
#define BATCH 64
#define ELEMS 196608          // C*H*W = 3*256*256
#define EPSV  1e-6f

// ---- pass 1 geometry (strided batch-reduction over `un` only) ----
#define POSB  256             // positions per block = 64 lanes * 4 (float4)
#define NBLK1 (ELEMS / POSB)  // 768 blocks
#define CHUNK 16              // batches per wave (4 waves cover 64)
#define GRP   4               // batches per pipeline stage

// ---- pass 2 geometry (streaming over clean/restored/s) ----
#define NSLAB  48             // slabs per batch
#define SLABSZ (ELEMS / NSLAB) // 4096 positions per slab (16 KB)
#define NBLK2  (BATCH * NSLAB) // 3072 blocks

// d_ws layout (floats):
//   s_buf  [NCAT][ELEMS]   = 983040   (per-cat scale map 1/un_map)
//   p1     [NCAT][NBLK1]   = 3840     (per-cat un sums)
//   p2     [2][NBLK2]      = 6144     (row0 = scaled sums, row1 = abs sums)
#define WS_S   0
#define WS_P1  (NCAT * ELEMS)
#define WS_P2  (WS_P1 + NCAT * NBLK1)

// ---------------------------------------------------------------------------
// Pass 1: un_sum[cat][pos] over batches (strided), invert to s, emit un sums.
// ---------------------------------------------------------------------------
__global__ __launch_bounds__(256) void pass1_kernel(
    const float* __restrict__ un,
    const int*   __restrict__ de_id,
    float*       __restrict__ s_buf,
    float*       __restrict__ p1)
{
    __shared__ int    sh_de[BATCH];
    __shared__ float  sh_inv[NCAT];
    __shared__ float4 sbuf[2][NCAT][64];

    const int tid  = threadIdx.x;
    const int lane = tid & 63;
    const int wave = tid >> 6;

    if (tid < BATCH) {
        int k = de_id[tid];
        sh_de[tid] = k;
        #pragma unroll
        for (int j = 0; j < NCAT; ++j) {
            unsigned long long m = __ballot(k == j);
            if (tid == j) {
                int c = __popcll(m);
                sh_inv[j] = 1.0f / (float)(c > 0 ? c : 1);
            }
        }
    }
    __syncthreads();

    const size_t base = (size_t)(wave * CHUNK) * ELEMS
                      + (size_t)blockIdx.x * POSB + (size_t)lane * 4;
    const float4* up = (const float4*)(un + base);
    const size_t STR4 = ELEMS / 4;

    float acc_un[NCAT][4];
    #pragma unroll
    for (int j = 0; j < NCAT; ++j)
        #pragma unroll
        for (int ii = 0; ii < 4; ++ii) acc_un[j][ii] = 0.f;

    float4 ub[2][GRP];
    #pragma unroll
    for (int i = 0; i < GRP; ++i) ub[0][i] = up[(size_t)i * STR4];

    #pragma unroll
    for (int g = 0; g < CHUNK / GRP; ++g) {
        const int cur = g & 1;
        const int nxt = cur ^ 1;
        if (g < CHUNK / GRP - 1) {
            #pragma unroll
            for (int i = 0; i < GRP; ++i)
                ub[nxt][i] = up[(size_t)((g + 1) * GRP + i) * STR4];
        }
        #pragma unroll
        for (int i = 0; i < GRP; ++i) {
            float4 u = ub[cur][i];
            int    k = sh_de[wave * CHUNK + g * GRP + i];
            #pragma unroll
            for (int j = 0; j < NCAT; ++j) {
                float m = (k == j) ? 1.0f : 0.0f;
                acc_un[j][0] = fmaf(m, u.x, acc_un[j][0]);
                acc_un[j][1] = fmaf(m, u.y, acc_un[j][1]);
                acc_un[j][2] = fmaf(m, u.z, acc_un[j][2]);
                acc_un[j][3] = fmaf(m, u.w, acc_un[j][3]);
            }
        }
    }

    // combine 4 batch-chunks into wave 0
    if (wave >= 2) {
        #pragma unroll
        for (int j = 0; j < NCAT; ++j)
            sbuf[wave - 2][j][lane] =
                make_float4(acc_un[j][0], acc_un[j][1], acc_un[j][2], acc_un[j][3]);
    }
    __syncthreads();
    if (wave < 2) {
        #pragma unroll
        for (int j = 0; j < NCAT; ++j) {
            float4 t = sbuf[wave][j][lane];
            acc_un[j][0] += t.x; acc_un[j][1] += t.y;
            acc_un[j][2] += t.z; acc_un[j][3] += t.w;
        }
    }
    __syncthreads();
    if (wave == 1) {
        #pragma unroll
        for (int j = 0; j < NCAT; ++j)
            sbuf[0][j][lane] =
                make_float4(acc_un[j][0], acc_un[j][1], acc_un[j][2], acc_un[j][3]);
    }
    __syncthreads();
    if (wave == 0) {
        float vals[NCAT];
        #pragma unroll
        for (int j = 0; j < NCAT; ++j) {
            float4 t = sbuf[0][j][lane];
            acc_un[j][0] += t.x; acc_un[j][1] += t.y;
            acc_un[j][2] += t.z; acc_un[j][3] += t.w;

            float um0 = fmaf(acc_un[j][0], sh_inv[j], EPSV);
            float um1 = fmaf(acc_un[j][1], sh_inv[j], EPSV);
            float um2 = fmaf(acc_un[j][2], sh_inv[j], EPSV);
            float um3 = fmaf(acc_un[j][3], sh_inv[j], EPSV);
            float4 sv = make_float4(1.f / um0, 1.f / um1, 1.f / um2, 1.f / um3);
            *(float4*)(s_buf + (size_t)j * ELEMS
                       + (size_t)blockIdx.x * POSB + (size_t)lane * 4) = sv;

            vals[j] = acc_un[j][0] + acc_un[j][1] + acc_un[j][2] + acc_un[j][3];
        }

        #pragma unroll
        for (int i = 0; i < NCAT; ++i) {
            float v = vals[i];
            #pragma unroll
            for (int off = 32; off >= 1; off >>= 1)
                v += __shfl_down(v, off, 64);
            vals[i] = v;
        }
        if (lane == 0) {
            #pragma unroll
            for (int i = 0; i < NCAT; ++i)
                p1[i * NBLK1 + blockIdx.x] = vals[i];
        }
    }
}

// ---------------------------------------------------------------------------
// Pass 2: streaming |clean-restored| and |.|*s over contiguous slabs.
// ---------------------------------------------------------------------------
__global__ __launch_bounds__(256) void pass2_kernel(
    const float* __restrict__ restored,
    const float* __restrict__ clean,
    const int*   __restrict__ de_id,
    const float* __restrict__ s_buf,
    float*       __restrict__ p2)
{
    __shared__ float sred[4][2];

    const int tid  = threadIdx.x;
    const int lane = tid & 63;
    const int wave = tid >> 6;

    const int b   = blockIdx.x / NSLAB;
    const int sl  = blockIdx.x % NSLAB;
    const int cat = de_id[b];                 // wave-uniform scalar

    const size_t pbase = (size_t)sl * SLABSZ + (size_t)wave * (SLABSZ / 4)
                       + (size_t)lane * 4;
    const float4* cp = (const float4*)(clean    + (size_t)b   * ELEMS + pbase);
    const float4* rp = (const float4*)(restored + (size_t)b   * ELEMS + pbase);
    const float4* sp = (const float4*)(s_buf    + (size_t)cat * ELEMS + pbase);

    float ssum = 0.f, asum = 0.f;
    // (SLABSZ/4)/4 positions per lane / 4 per float4 = 4 iterations
    #pragma unroll
    for (int it = 0; it < SLABSZ / 4 / 256; ++it) {
        float4 c  = cp[it * 64];
        float4 r  = rp[it * 64];
        float4 sv = sp[it * 64];
        float a0 = fabsf(c.x - r.x);
        float a1 = fabsf(c.y - r.y);
        float a2 = fabsf(c.z - r.z);
        float a3 = fabsf(c.w - r.w);
        asum += (a0 + a1) + (a2 + a3);
        ssum = fmaf(a0, sv.x, ssum);
        ssum = fmaf(a1, sv.y, ssum);
        ssum = fmaf(a2, sv.z, ssum);
        ssum = fmaf(a3, sv.w, ssum);
    }

    #pragma unroll
    for (int off = 32; off >= 1; off >>= 1) {
        ssum += __shfl_down(ssum, off, 64);
        asum += __shfl_down(asum, off, 64);
    }
    if (lane == 0) { sred[wave][0] = ssum; sred[wave][1] = asum; }
    __syncthreads();
    if (tid == 0) {
        float s = sred[0][0] + sred[1][0] + sred[2][0] + sred[3][0];
        float a = sred[0][1] + sred[1][1] + sred[2][1] + sred[3][1];
        p2[blockIdx.x]         = s;
        p2[NBLK2 + blockIdx.x] = a;
    }
}

// ---------------------------------------------------------------------------
// Epilogue: gather p2 by category, reduce p1, final 21-output math.
// ---------------------------------------------------------------------------
__global__ __launch_bounds__(1024) void epilogue_kernel(
    const int*   __restrict__ de_id,
    const float* __restrict__ p1,
    const float* __restrict__ p2,
    float*       __restrict__ out)
{
    __shared__ int   sh_cnt[NCAT];
    __shared__ int   sh_cat[BATCH];
    __shared__ float sh_acc[3 * NCAT];

    const int tid  = threadIdx.x;
    const int lane = tid & 63;
    const int wave = tid >> 6;

    if (tid < BATCH) {
        int k = de_id[tid];
        sh_cat[tid] = k;
        #pragma unroll
        for (int j = 0; j < NCAT; ++j) {
            unsigned long long m = __ballot(k == j);
            if (tid == j) sh_cnt[j] = __popcll(m);
        }
    }
    __syncthreads();

    float v = 0.f;
    if (wave < 5) {                       // scaled sums per cat
        for (int it = 0; it < NBLK2 / 64; ++it) {
            int col = it * 64 + lane;
            v += (sh_cat[col / NSLAB] == wave) ? p2[col] : 0.f;
        }
    } else if (wave < 10) {               // abs sums per cat
        const int j = wave - 5;
        for (int it = 0; it < NBLK2 / 64; ++it) {
            int col = it * 64 + lane;
            v += (sh_cat[col / NSLAB] == j) ? p2[NBLK2 + col] : 0.f;
        }
    } else if (wave < 15) {               // un sums per cat
        const int j = wave - 10;
        for (int it = 0; it < NBLK1 / 64; ++it)
            v += p1[j * NBLK1 + it * 64 + lane];
    }
    #pragma unroll
    for (int off = 32; off >= 1; off >>= 1)
        v += __shfl_down(v, off, 64);
    if (lane == 0 && wave < 15) sh_acc[wave] = v;
    __syncthreads();

    if (tid == 0) {
        const float Ef = (float)ELEMS;
        float cum_s = 0.f;
        long  cum_c = 0;
        float total = 0.f;
        int   num   = 0;

        float cat_losses[NCAT], old_loss[NCAT], bn[NCAT], unc_l1[NCAT];

        for (int j = 0; j < NCAT; ++j) {
            cum_s += sh_acc[j];
            cum_c += sh_cnt[j];
            float cum_elems = (float)cum_c * Ef;
            float cum_l1    = cum_s / fmaxf(cum_elems, 1.0f);

            bool  ne   = sh_cnt[j] > 0;
            float safe = (float)(ne ? sh_cnt[j] : 1);

            old_loss[j]  = ne ? sh_acc[NCAT + j] / (safe * Ef) : 0.f;
            float un_num = sh_acc[2 * NCAT + j] / (safe * Ef) + EPSV;
            bn[j]        = ne ? 2.0f * logf(un_num) : 0.f;
            unc_l1[j]    = ne ? cum_l1 : 0.f;
            cat_losses[j] = unc_l1[j] + bn[j];
            total += cat_losses[j];
            num   += ne ? 1 : 0;
        }
        total /= (float)num;

        out[0] = total;
        for (int j = 0; j < NCAT; ++j) {
            out[1 + j]  = cat_losses[j];
            out[6 + j]  = old_loss[j];
            out[11 + j] = bn[j];
            out[16 + j] = unc_l1[j];
        }
    }
}

extern "C" void kernel_launch(void* const* d_in, const int* in_sizes, int n_in,
                              void* d_out, int out_size, void* d_ws, size_t ws_size,
                              hipStream_t stream) {
    (void)in_sizes; (void)n_in; (void)out_size; (void)ws_size;
    const float* restored = (const float*)d_in[0];
    const float* clean    = (const float*)d_in[1];
    const int*   de_id    = (const int*)d_in[2];
    const float* un       = (const float*)d_in[3];
    float* out   = (float*)d_out;
    float* ws    = (float*)d_ws;
    float* s_buf = ws + WS_S;
    float* p1    = ws + WS_P1;
    float* p2    = ws + WS_P2;

    pass1_kernel<<<NBLK1, 256, 0, stream>>>(un, de_id, s_buf, p1);
    pass2_kernel<<<NBLK2, 256, 0, stream>>>(restored, clean, de_id, s_buf, p2);
    epilogue_kernel<<<1, 1024, 0, stream>>>(de_id, p1, p2, out);
}

// Round 5
// 160.614 us; speedup vs baseline: 1.0828x; 1.0828x over previous
//
#include <hip/hip_runtime.h>
#include <math.h>

#define NCAT  5
#define BATCH 64
#define ELEMS 196608          // C*H*W = 3*256*256
#define EPSV  1e-6f

// native 4-float vector for nontemporal builtins (HIP float4 is a class)
typedef float v4f __attribute__((ext_vector_type(4)));

// ---- pass 1 geometry (strided batch-reduction over `un` only) ----
#define POSB  256             // positions per block = 64 lanes * 4 (float4)
#define NBLK1 (ELEMS / POSB)  // 768 blocks
#define CHUNK 16              // batches per wave (4 waves cover 64)
#define GRP   4               // batches per pipeline stage

// ---- pass 2 geometry (streaming over clean/restored/s) ----
#define NSLAB  12              // slabs per batch (fat blocks: 64 KB/array/block)
#define SLABSZ (ELEMS / NSLAB) // 16384 positions per slab
#define NBLK2  (BATCH * NSLAB) // 768 blocks

// d_ws layout (floats):
//   s_buf  [NCAT][ELEMS]   (per-cat scale map 1/un_map)
//   p1     [NCAT][NBLK1]   (per-cat un sums)
//   p2     [2][NBLK2]      (row0 = scaled sums, row1 = abs sums)
#define WS_S   0
#define WS_P1  (NCAT * ELEMS)
#define WS_P2  (WS_P1 + NCAT * NBLK1)

// ---------------------------------------------------------------------------
// Pass 1: un_sum[cat][pos] over batches (strided), invert to s, emit un sums.
// ---------------------------------------------------------------------------
__global__ __launch_bounds__(256) void pass1_kernel(
    const float* __restrict__ un,
    const int*   __restrict__ de_id,
    float*       __restrict__ s_buf,
    float*       __restrict__ p1)
{
    __shared__ int    sh_de[BATCH];
    __shared__ float  sh_inv[NCAT];
    __shared__ float4 sbuf[2][NCAT][64];

    const int tid  = threadIdx.x;
    const int lane = tid & 63;
    const int wave = tid >> 6;

    if (tid < BATCH) {
        int k = de_id[tid];
        sh_de[tid] = k;
        #pragma unroll
        for (int j = 0; j < NCAT; ++j) {
            unsigned long long m = __ballot(k == j);
            if (tid == j) {
                int c = __popcll(m);
                sh_inv[j] = 1.0f / (float)(c > 0 ? c : 1);
            }
        }
    }
    __syncthreads();

    const size_t base = (size_t)(wave * CHUNK) * ELEMS
                      + (size_t)blockIdx.x * POSB + (size_t)lane * 4;
    const float4* up = (const float4*)(un + base);
    const size_t STR4 = ELEMS / 4;

    float acc_un[NCAT][4];
    #pragma unroll
    for (int j = 0; j < NCAT; ++j)
        #pragma unroll
        for (int ii = 0; ii < 4; ++ii) acc_un[j][ii] = 0.f;

    float4 ub[2][GRP];
    #pragma unroll
    for (int i = 0; i < GRP; ++i) ub[0][i] = up[(size_t)i * STR4];

    #pragma unroll
    for (int g = 0; g < CHUNK / GRP; ++g) {
        const int cur = g & 1;
        const int nxt = cur ^ 1;
        if (g < CHUNK / GRP - 1) {
            #pragma unroll
            for (int i = 0; i < GRP; ++i)
                ub[nxt][i] = up[(size_t)((g + 1) * GRP + i) * STR4];
        }
        #pragma unroll
        for (int i = 0; i < GRP; ++i) {
            float4 u = ub[cur][i];
            int    k = sh_de[wave * CHUNK + g * GRP + i];
            #pragma unroll
            for (int j = 0; j < NCAT; ++j) {
                float m = (k == j) ? 1.0f : 0.0f;
                acc_un[j][0] = fmaf(m, u.x, acc_un[j][0]);
                acc_un[j][1] = fmaf(m, u.y, acc_un[j][1]);
                acc_un[j][2] = fmaf(m, u.z, acc_un[j][2]);
                acc_un[j][3] = fmaf(m, u.w, acc_un[j][3]);
            }
        }
    }

    // combine 4 batch-chunks into wave 0
    if (wave >= 2) {
        #pragma unroll
        for (int j = 0; j < NCAT; ++j)
            sbuf[wave - 2][j][lane] =
                make_float4(acc_un[j][0], acc_un[j][1], acc_un[j][2], acc_un[j][3]);
    }
    __syncthreads();
    if (wave < 2) {
        #pragma unroll
        for (int j = 0; j < NCAT; ++j) {
            float4 t = sbuf[wave][j][lane];
            acc_un[j][0] += t.x; acc_un[j][1] += t.y;
            acc_un[j][2] += t.z; acc_un[j][3] += t.w;
        }
    }
    __syncthreads();
    if (wave == 1) {
        #pragma unroll
        for (int j = 0; j < NCAT; ++j)
            sbuf[0][j][lane] =
                make_float4(acc_un[j][0], acc_un[j][1], acc_un[j][2], acc_un[j][3]);
    }
    __syncthreads();
    if (wave == 0) {
        float vals[NCAT];
        #pragma unroll
        for (int j = 0; j < NCAT; ++j) {
            float4 t = sbuf[0][j][lane];
            acc_un[j][0] += t.x; acc_un[j][1] += t.y;
            acc_un[j][2] += t.z; acc_un[j][3] += t.w;

            float um0 = fmaf(acc_un[j][0], sh_inv[j], EPSV);
            float um1 = fmaf(acc_un[j][1], sh_inv[j], EPSV);
            float um2 = fmaf(acc_un[j][2], sh_inv[j], EPSV);
            float um3 = fmaf(acc_un[j][3], sh_inv[j], EPSV);
            float4 sv = make_float4(1.f / um0, 1.f / um1, 1.f / um2, 1.f / um3);
            *(float4*)(s_buf + (size_t)j * ELEMS
                       + (size_t)blockIdx.x * POSB + (size_t)lane * 4) = sv;

            vals[j] = acc_un[j][0] + acc_un[j][1] + acc_un[j][2] + acc_un[j][3];
        }

        #pragma unroll
        for (int i = 0; i < NCAT; ++i) {
            float v = vals[i];
            #pragma unroll
            for (int off = 32; off >= 1; off >>= 1)
                v += __shfl_down(v, off, 64);
            vals[i] = v;
        }
        if (lane == 0) {
            #pragma unroll
            for (int i = 0; i < NCAT; ++i)
                p1[i * NBLK1 + blockIdx.x] = vals[i];
        }
    }
}

// ---------------------------------------------------------------------------
// Pass 2: streaming |clean-restored| and |.|*s over fat contiguous slabs.
// ---------------------------------------------------------------------------
__global__ __launch_bounds__(256) void pass2_kernel(
    const float* __restrict__ restored,
    const float* __restrict__ clean,
    const int*   __restrict__ de_id,
    const float* __restrict__ s_buf,
    float*       __restrict__ p2)
{
    __shared__ float sred[4][2];

    const int tid  = threadIdx.x;
    const int lane = tid & 63;
    const int wave = tid >> 6;

    const int b   = blockIdx.x / NSLAB;
    const int sl  = blockIdx.x % NSLAB;
    const int cat = de_id[b];                 // block-uniform scalar

    // float4-unit base: slab sl, wave-quarter, lane
    const size_t base4 = (size_t)sl * (SLABSZ / 4) + (size_t)wave * (SLABSZ / 16)
                       + (size_t)lane;
    const v4f* cp = (const v4f*)(clean)    + (size_t)b   * (ELEMS / 4) + base4;
    const v4f* rp = (const v4f*)(restored) + (size_t)b   * (ELEMS / 4) + base4;
    const v4f* sp = (const v4f*)(s_buf)    + (size_t)cat * (ELEMS / 4) + base4;

    float ssum = 0.f, asum = 0.f;
    // (SLABSZ/16) float4 per wave / 64 lanes = 16 iterations
    #pragma unroll 16
    for (int it = 0; it < SLABSZ / 16 / 64; ++it) {
        v4f c  = __builtin_nontemporal_load(cp + it * 64);   // read-once
        v4f r  = __builtin_nontemporal_load(rp + it * 64);   // read-once
        v4f sv = sp[it * 64];                                // L2/L3-hot
        float a0 = fabsf(c.x - r.x);
        float a1 = fabsf(c.y - r.y);
        float a2 = fabsf(c.z - r.z);
        float a3 = fabsf(c.w - r.w);
        asum += (a0 + a1) + (a2 + a3);
        ssum = fmaf(a0, sv.x, ssum);
        ssum = fmaf(a1, sv.y, ssum);
        ssum = fmaf(a2, sv.z, ssum);
        ssum = fmaf(a3, sv.w, ssum);
    }

    #pragma unroll
    for (int off = 32; off >= 1; off >>= 1) {
        ssum += __shfl_down(ssum, off, 64);
        asum += __shfl_down(asum, off, 64);
    }
    if (lane == 0) { sred[wave][0] = ssum; sred[wave][1] = asum; }
    __syncthreads();
    if (tid == 0) {
        float s = sred[0][0] + sred[1][0] + sred[2][0] + sred[3][0];
        float a = sred[0][1] + sred[1][1] + sred[2][1] + sred[3][1];
        p2[blockIdx.x]         = s;
        p2[NBLK2 + blockIdx.x] = a;
    }
}

// ---------------------------------------------------------------------------
// Epilogue: gather p2 by category, reduce p1, final 21-output math.
// ---------------------------------------------------------------------------
__global__ __launch_bounds__(1024) void epilogue_kernel(
    const int*   __restrict__ de_id,
    const float* __restrict__ p1,
    const float* __restrict__ p2,
    float*       __restrict__ out)
{
    __shared__ int   sh_cnt[NCAT];
    __shared__ int   sh_cat[BATCH];
    __shared__ float sh_acc[3 * NCAT];

    const int tid  = threadIdx.x;
    const int lane = tid & 63;
    const int wave = tid >> 6;

    if (tid < BATCH) {
        int k = de_id[tid];
        sh_cat[tid] = k;
        #pragma unroll
        for (int j = 0; j < NCAT; ++j) {
            unsigned long long m = __ballot(k == j);
            if (tid == j) sh_cnt[j] = __popcll(m);
        }
    }
    __syncthreads();

    float v = 0.f;
    if (wave < 5) {                       // scaled sums per cat
        for (int it = 0; it < NBLK2 / 64; ++it) {
            int col = it * 64 + lane;
            v += (sh_cat[col / NSLAB] == wave) ? p2[col] : 0.f;
        }
    } else if (wave < 10) {               // abs sums per cat
        const int j = wave - 5;
        for (int it = 0; it < NBLK2 / 64; ++it) {
            int col = it * 64 + lane;
            v += (sh_cat[col / NSLAB] == j) ? p2[NBLK2 + col] : 0.f;
        }
    } else if (wave < 15) {               // un sums per cat
        const int j = wave - 10;
        for (int it = 0; it < NBLK1 / 64; ++it)
            v += p1[j * NBLK1 + it * 64 + lane];
    }
    #pragma unroll
    for (int off = 32; off >= 1; off >>= 1)
        v += __shfl_down(v, off, 64);
    if (lane == 0 && wave < 15) sh_acc[wave] = v;
    __syncthreads();

    if (tid == 0) {
        const float Ef = (float)ELEMS;
        float cum_s = 0.f;
        long  cum_c = 0;
        float total = 0.f;
        int   num   = 0;

        float cat_losses[NCAT], old_loss[NCAT], bn[NCAT], unc_l1[NCAT];

        for (int j = 0; j < NCAT; ++j) {
            cum_s += sh_acc[j];
            cum_c += sh_cnt[j];
            float cum_elems = (float)cum_c * Ef;
            float cum_l1    = cum_s / fmaxf(cum_elems, 1.0f);

            bool  ne   = sh_cnt[j] > 0;
            float safe = (float)(ne ? sh_cnt[j] : 1);

            old_loss[j]  = ne ? sh_acc[NCAT + j] / (safe * Ef) : 0.f;
            float un_num = sh_acc[2 * NCAT + j] / (safe * Ef) + EPSV;
            bn[j]        = ne ? 2.0f * logf(un_num) : 0.f;
            unc_l1[j]    = ne ? cum_l1 : 0.f;
            cat_losses[j] = unc_l1[j] + bn[j];
            total += cat_losses[j];
            num   += ne ? 1 : 0;
        }
        total /= (float)num;

        out[0] = total;
        for (int j = 0; j < NCAT; ++j) {
            out[1 + j]  = cat_losses[j];
            out[6 + j]  = old_loss[j];
            out[11 + j] = bn[j];
            out[16 + j] = unc_l1[j];
        }
    }
}

extern "C" void kernel_launch(void* const* d_in, const int* in_sizes, int n_in,
                              void* d_out, int out_size, void* d_ws, size_t ws_size,
                              hipStream_t stream) {
    (void)in_sizes; (void)n_in; (void)out_size; (void)ws_size;
    const float* restored = (const float*)d_in[0];
    const float* clean    = (const float*)d_in[1];
    const int*   de_id    = (const int*)d_in[2];
    const float* un       = (const float*)d_in[3];
    float* out   = (float*)d_out;
    float* ws    = (float*)d_ws;
    float* s_buf = ws + WS_S;
    float* p1    = ws + WS_P1;
    float* p2    = ws + WS_P2;

    pass1_kernel<<<NBLK1, 256, 0, stream>>>(un, de_id, s_buf, p1);
    pass2_kernel<<<NBLK2, 256, 0, stream>>>(restored, clean, de_id, s_buf, p2);
    epilogue_kernel<<<1, 1024, 0, stream>>>(de_id, p1, p2, out);
}